// Round 4
// baseline (2535.964 us; speedup 1.0000x reference)
//
#include <hip/hip_runtime.h>

typedef __bf16 bf16x8 __attribute__((ext_vector_type(8)));
typedef float  f32x4  __attribute__((ext_vector_type(4)));

union U4 { uint4 u; bf16x8 v; };

__device__ __forceinline__ bf16x8 ld_frag(const void* p) {
    U4 t; t.u = *(const uint4*)p; return t.v;
}
__device__ __forceinline__ bf16x8 zfrag() {
    bf16x8 z;
#pragma unroll
    for (int jj = 0; jj < 8; jj++) z[jj] = (__bf16)0.f;
    return z;
}

__device__ __forceinline__ void gl_lds16(const uint4* g, void* l) {
    __builtin_amdgcn_global_load_lds(
        (const __attribute__((address_space(1))) unsigned int*)g,
        (__attribute__((address_space(3))) unsigned int*)l, 16, 0, 0);
}

__device__ __forceinline__ float sigf(float x) {
    return __builtin_amdgcn_rcpf(1.f + __expf(-x));
}
__device__ __forceinline__ float tanhf_fast(float x) {
    return 1.f - 2.f * __builtin_amdgcn_rcpf(1.f + __expf(2.f * x));
}

#define MFMA(A,B,C) C = __builtin_amdgcn_mfma_f32_16x16x32_bf16(A, B, C, 0, 0, 0)

// ---------------------------------------------------------------------------
// Pack [Wx (16 rows, pad to 32); Uh (256); Uh2 (256)] -> K=544 rows x 768 cols
// per direction, as B-fragments:
// pack[a][kt(17)][nt(48)][lane(64)] = 8 bf16 : B[kt*32+(lane>>4)*8+j][nt*16+(lane&15)]
// ---------------------------------------------------------------------------
__global__ void pack_kernel(const float* __restrict__ Wx, const float* __restrict__ Uh,
                            const float* __restrict__ Uh2, uint4* __restrict__ packW) {
    int tid = blockIdx.x * 256 + threadIdx.x;   // exactly 4*17*48*64 = 208896 threads
    int lane = tid & 63;
    int nt   = (tid >> 6) % 48;
    int kt   = ((tid >> 6) / 48) % 17;
    int a    = (tid >> 6) / (48 * 17);
    int col  = nt * 16 + (lane & 15);
    int kbase = kt * 32 + (lane >> 4) * 8;
    U4 u;
#pragma unroll
    for (int jj = 0; jj < 8; jj++) {
        int k = kbase + jj;
        float v;
        if (k < 16)       v = Wx[(a * 16 + k) * 768 + col];
        else if (k < 32)  v = 0.f;
        else if (k < 288) v = Uh[(a * 256 + (k - 32)) * 768 + col];
        else              v = Uh2[(a * 256 + (k - 288)) * 768 + col];
        u.v[jj] = (__bf16)v;
    }
    packW[tid] = u.u;
}

// ---------------------------------------------------------------------------
// Pack x patches into A-fragment layout:
// xpack[a][i(29)][j(29)][m(256)][q(2)] = uint4 (8 bf16): patch element k=q*8+jj
// ---------------------------------------------------------------------------
__global__ void xpack_kernel(const float* __restrict__ x, uint4* __restrict__ xp) {
    int tid = blockIdx.x * 256 + threadIdx.x;   // 4*29*29*256*2 = 1,722,368 threads
    int q = tid & 1;
    int m = (tid >> 1) & 255;
    int rem = tid >> 9;                          // a*841 + i*29 + j
    int j = rem % 29;
    int t2 = rem / 29;
    int i = t2 % 29;
    int a = t2 / 29;
    int Ny = 29 - (a & 1), Nx = 29 - ((a >> 1) & 1);
    U4 u;
    if (i < Ny && j < Nx) {
        int y0 = (a & 1) ? (27 - i) : i;
        int x0 = (a & 2) ? (27 - j) : j;
        const float* px = x + m * 1024 + y0 * 32 + x0;
#pragma unroll
        for (int jj = 0; jj < 8; jj++) {
            int k = q * 8 + jj;
            u.v[jj] = (__bf16)px[(k >> 2) * 32 + (k & 3)];
        }
    } else {
#pragma unroll
        for (int jj = 0; jj < 8; jj++) u.v[jj] = (__bf16)0.f;
    }
    xp[tid] = u.u;
}

// ---------------------------------------------------------------------------
// Wavefront kernel v3. Block = cell (a,i,j) x 64-hidden-col group t (0..3).
// Block covers M=256 x N=192 (64 cols per gate). 4 waves; wave wm: rows [64wm,64wm+64).
// acc[mt][c], c = gate*4+u: gate in {r,z,n}, u = 16-col subtile (cols t*64+u*16+l16).
// x-stage (kt=0) deferred to the END: r,z accumulate into acc, n-part per-u into tmp,
// fused with the gate epilogue (removes extra n_x acc tiles).
// XCD swizzle by j-parity: bx = 8*slot + (2a+(j&1)), slot = cellidx*4 + t.
//   -> writer of slice j and its hA-reader (cell (i+1,j), next diag) share an XCD.
// B double-buffered in LDS via global_load_lds (12 chunks x 1KB per stage).
// hbuf layout (k-major per slice): [parity 2][a 4][j 29][kt 8][m 256][c32 32] bf16
// ---------------------------------------------------------------------------
__global__ __launch_bounds__(256, 2) void wf_kernel(
    const float* __restrict__ x, const uint4* __restrict__ xpack,
    const uint4* __restrict__ packW, const float* __restrict__ bias,
    __bf16* __restrict__ hbuf, int d, int4 jlo4, int4 jhi4)
{
    __shared__ __align__(16) unsigned char smemB[24576];   // 2 bufs x 12 KB

    int bx   = blockIdx.x;
    int xcd  = bx & 7;
    int a    = xcd >> 1;
    int p    = xcd & 1;
    int slot = bx >> 3;
    int lo = (a == 0) ? jlo4.x : (a == 1) ? jlo4.y : (a == 2) ? jlo4.z : jlo4.w;
    int hi = (a == 0) ? jhi4.x : (a == 1) ? jhi4.y : (a == 2) ? jhi4.z : jhi4.w;
    if (hi < lo) return;
    int j0 = lo + (((lo & 1) ^ p) & 1);
    int j  = j0 + ((slot >> 2) << 1);
    if (j > hi) return;
    int t = slot & 3;
    int i = d - j;
    bool hasA = (i > 0);
    bool hasL = (j > 0);

    int tid  = threadIdx.x;
    int wm   = tid >> 6;         // 0..3: row group
    int lane = tid & 63;
    int q    = lane >> 4;
    int l16  = lane & 15;

    int pprev = (d - 1) & 1;
    int pcur  = d & 1;
    const char* hAB = (const char*)(hbuf + ((size_t)(pprev * 4 + a) * 29 + j) * 65536);
    const char* hLB = (const char*)(hbuf + ((size_t)(pprev * 4 + a) * 29 + (j - 1)) * 65536);

    f32x4 acc[4][12];
#pragma unroll
    for (int mt = 0; mt < 4; mt++)
#pragma unroll
        for (int c = 0; c < 12; c++)
#pragma unroll
            for (int e = 0; e < 4; e++) acc[mt][c][e] = 0.f;

    // stage s: 0..7 = hA (kt=s+1), 8..15 = hL (kt=s+1), 16 = x (kt=0)
    auto issueB = [&](int s) {
        int kt = (s == 16) ? 0 : (s + 1);
        const uint4* wb = packW + (size_t)(a * 17 + kt) * 3072;
        unsigned char* dst = smemB + (s & 1) * 12288;
#pragma unroll
        for (int e = 0; e < 3; e++) {
            int c  = wm * 3 + e;                    // chunk = gate*4 + u
            int nt = (c >> 2) * 16 + t * 4 + (c & 3);
            gl_lds16(wb + nt * 64 + lane, dst + c * 1024);
        }
    };

    issueB(0);

    for (int s = 0; s < 16; ++s) {
        __syncthreads();                            // buf[s&1] ready
        issueB(s + 1);
        bool act = (s < 8) ? hasA : hasL;
        if (act) {
            const char* base = ((s < 8) ? hAB : hLB) + (s & 7) * 16384 + q * 16;
            bf16x8 af[4];
#pragma unroll
            for (int mt = 0; mt < 4; mt++)
                af[mt] = ld_frag(base + (wm * 64 + mt * 16 + l16) * 64);
            const unsigned char* bb = smemB + (s & 1) * 12288 + lane * 16;
#pragma unroll
            for (int c = 0; c < 12; c++) {
                bf16x8 bf = ld_frag(bb + c * 1024);
#pragma unroll
                for (int mt = 0; mt < 4; mt++) MFMA(af[mt], bf, acc[mt][c]);
            }
        }
    }

    // ---- x-stage A fragments (loaded while stage-16 B drains) ----
    bf16x8 afx[4];
    if (xpack) {
        const uint4* xpc = xpack + (size_t)((a * 29 + i) * 29 + j) * 512 + q;
#pragma unroll
        for (int mt = 0; mt < 4; mt++) {
            if (q < 2) afx[mt] = ld_frag(xpc + (wm * 64 + mt * 16 + l16) * 2);
            else       afx[mt] = zfrag();
        }
    } else {
        int y0 = (a & 1) ? (27 - i) : i;
        int x0 = (a & 2) ? (27 - j) : j;
#pragma unroll
        for (int mt = 0; mt < 4; mt++) {
            if (q < 2) {
                int m = wm * 64 + mt * 16 + l16;
                const float* xp = x + m * 1024 + (y0 + 2 * q) * 32 + x0;
#pragma unroll
                for (int jj = 0; jj < 8; jj++)
                    afx[mt][jj] = (__bf16)xp[(jj >> 2) * 32 + (jj & 3)];
            } else afx[mt] = zfrag();
        }
    }

    __syncthreads();                                // stage-16 B in buf0 ready

    const unsigned char* bb0 = smemB + lane * 16;   // (16&1)==0
    // r,z gates: accumulate x contribution into acc
#pragma unroll
    for (int c = 0; c < 8; c++) {
        bf16x8 bf = ld_frag(bb0 + c * 1024);
#pragma unroll
        for (int mt = 0; mt < 4; mt++) MFMA(afx[mt], bf, acc[mt][c]);
    }

    // n gate per u-subtile, fused with epilogue
    const float* ba = bias + a * 768;
    char* houtB = (char*)(hbuf + ((size_t)(pcur * 4 + a) * 29 + j) * 65536);
#pragma unroll
    for (int u = 0; u < 4; u++) {
        bf16x8 bf = ld_frag(bb0 + (8 + u) * 1024);
        f32x4 tn[4];
#pragma unroll
        for (int mt = 0; mt < 4; mt++) {
            f32x4 z4 = {0.f, 0.f, 0.f, 0.f};
            tn[mt] = __builtin_amdgcn_mfma_f32_16x16x32_bf16(afx[mt], bf, z4, 0, 0, 0);
        }
        int c = t * 64 + u * 16 + l16;              // hidden col 0..255
        float bR = ba[c], bZ = ba[256 + c], bN = ba[512 + c];
        size_t cof = (size_t)(c >> 5) * 16384 + (size_t)(c & 31) * 2;
#pragma unroll
        for (int mt = 0; mt < 4; mt++) {
#pragma unroll
            for (int r2 = 0; r2 < 4; r2++) {
                int m = wm * 64 + mt * 16 + q * 4 + r2;
                size_t off = cof + (size_t)m * 64;
                float rv = sigf(acc[mt][u][r2] + bR);
                float zv = sigf(acc[mt][4 + u][r2] + bZ);
                float nv = tanhf_fast(tn[mt][r2] + bN + rv * acc[mt][8 + u][r2]);
                float hs = 0.f;
                if (hasA) hs += (float)(*(const __bf16*)(hAB + off));
                if (hasL) hs += (float)(*(const __bf16*)(hLB + off));
                *(__bf16*)(houtB + off) = (__bf16)((1.f - zv) * nv + 0.5f * zv * hs);
            }
        }
    }
}

// ---------------------------------------------------------------------------
// Output: logits = hcat @ W_out + b_out, then log_softmax. One wave per batch.
// hbuf slice layout is k-major: elem = (c>>5)*8192 + m*32 + (c&31)
// ---------------------------------------------------------------------------
__global__ __launch_bounds__(64) void out_kernel(const __bf16* __restrict__ hbuf,
    const float* __restrict__ Wout, const float* __restrict__ bout,
    float* __restrict__ out)
{
    int b = blockIdx.x;
    int tt = threadIdx.x;
    float accv[10];
#pragma unroll
    for (int o = 0; o < 10; o++) accv[o] = 0.f;
    for (int it = 0; it < 16; ++it) {
        int k = it * 64 + tt;
        int a = k >> 8, c = k & 255;
        int Ny = 29 - (a & 1), Nx = 29 - ((a >> 1) & 1);
        int pf = (Ny + Nx - 2) & 1;
        int jf = Nx - 1;
        float h = (float)hbuf[((size_t)(pf * 4 + a) * 29 + jf) * 65536
                              + (size_t)(c >> 5) * 8192 + (size_t)b * 32 + (c & 31)];
        const float* wr = Wout + k * 10;
#pragma unroll
        for (int o = 0; o < 10; o++) accv[o] += h * wr[o];
    }
#pragma unroll
    for (int off = 32; off > 0; off >>= 1)
#pragma unroll
        for (int o = 0; o < 10; o++) accv[o] += __shfl_down(accv[o], off, 64);
    if (tt == 0) {
        float l[10];
#pragma unroll
        for (int o = 0; o < 10; o++) l[o] = accv[o] + bout[o];
        float mx = l[0];
#pragma unroll
        for (int o = 1; o < 10; o++) mx = fmaxf(mx, l[o]);
        float se = 0.f;
#pragma unroll
        for (int o = 0; o < 10; o++) se += __expf(l[o] - mx);
        float lse = mx + __logf(se);
#pragma unroll
        for (int o = 0; o < 10; o++) out[b * 10 + o] = l[o] - lse;
    }
}

extern "C" void kernel_launch(void* const* d_in, const int* in_sizes, int n_in,
                              void* d_out, int out_size, void* d_ws, size_t ws_size,
                              hipStream_t stream) {
    const float* x    = (const float*)d_in[0];
    const float* Wx   = (const float*)d_in[1];
    const float* Uh   = (const float*)d_in[2];
    const float* Uh2  = (const float*)d_in[3];
    const float* b    = (const float*)d_in[4];
    const float* Wout = (const float*)d_in[5];
    const float* bout = (const float*)d_in[6];
    float* out = (float*)d_out;

    char* ws = (char*)d_ws;
    const size_t XPACK_OFF = 3407872;
    const size_t HBUF_OFF_BIG = 31457280;
    const size_t NEED = HBUF_OFF_BIG + 30408704;
    bool use_xp = (ws_size >= NEED);

    uint4*  packW = (uint4*)ws;
    uint4*  xpack = use_xp ? (uint4*)(ws + XPACK_OFF) : nullptr;
    __bf16* hbuf  = (__bf16*)(ws + (use_xp ? HBUF_OFF_BIG : XPACK_OFF));

    pack_kernel<<<816, 256, 0, stream>>>(Wx, Uh, Uh2, packW);
    if (use_xp)
        xpack_kernel<<<6728, 256, 0, stream>>>(x, xpack);

    for (int d = 0; d < 57; ++d) {
        int jlo[4], jhi[4]; int maxcnt = 0;
        for (int a = 0; a < 4; a++) {
            int Ny = 29 - (a & 1), Nx = 29 - ((a >> 1) & 1);
            int lo = d - (Ny - 1); if (lo < 0) lo = 0;
            int hi = (d < Nx - 1) ? d : Nx - 1;
            jlo[a] = lo; jhi[a] = hi;
            if (hi >= lo) {
                for (int p = 0; p < 2; p++) {
                    int j0 = lo + (((lo & 1) ^ p) & 1);
                    int c = (hi >= j0) ? ((hi - j0) >> 1) + 1 : 0;
                    if (c > maxcnt) maxcnt = c;
                }
            }
        }
        int grid = 32 * maxcnt;     // 8 xcd-slots x 4 t x maxcnt cells
        wf_kernel<<<grid, 256, 0, stream>>>(x, xpack, packW, b, hbuf, d,
            make_int4(jlo[0], jlo[1], jlo[2], jlo[3]),
            make_int4(jhi[0], jhi[1], jhi[2], jhi[3]));
    }
    out_kernel<<<256, 64, 0, stream>>>(hbuf, Wout, bout, out);
}